// Round 1
// baseline (377.890 us; speedup 1.0000x reference)
//
#include <hip/hip_runtime.h>
#include <stdint.h>

typedef __attribute__((ext_vector_type(4))) float f32x4;
typedef __attribute__((ext_vector_type(4))) unsigned int u32x4;
typedef __attribute__((ext_vector_type(8))) __bf16 bf16x8;

#define NB 8
#define SQ 2048
#define DM 1024

// Fragment read from a [R][64] bf16 LDS tile (row stride 128 B) with XOR swizzle:
// logical chunk c (8 bf16 = 16 B) of row r lives at physical chunk c ^ (r & 7).
__device__ __forceinline__ bf16x8 ldfrag(const __bf16* base, int row, int chunk) {
  const char* p = (const char*)base + row * 128 + ((chunk ^ (row & 7)) << 4);
  return *(const bf16x8*)p;
}

// ---------------- fp32 -> bf16 convert (8 elems / thread) ----------------
__global__ void k_convert(const float* __restrict__ src, __bf16* __restrict__ dst) {
  size_t i = (size_t)blockIdx.x * blockDim.x + threadIdx.x;
  const f32x4* s = (const f32x4*)src + i * 2;
  f32x4 a = s[0], b = s[1];
  bf16x8 o;
  o[0] = (__bf16)a[0]; o[1] = (__bf16)a[1]; o[2] = (__bf16)a[2]; o[3] = (__bf16)a[3];
  o[4] = (__bf16)b[0]; o[5] = (__bf16)b[1]; o[6] = (__bf16)b[2]; o[7] = (__bf16)b[3];
  *((bf16x8*)dst + i) = o;
}

// ---------------- tail [b][h][d] f32 -> Vt [b][d][h] bf16 ----------------
__global__ void k_transpose(const float* __restrict__ V, __bf16* __restrict__ Vt) {
  __shared__ alignas(16) __bf16 sT[64 * 72];  // [d][h] tile, padded rows (72)
  const int tid = threadIdx.x;
  const int d0 = blockIdx.x * 64, h0 = blockIdx.y * 64, b = blockIdx.z;
#pragma unroll
  for (int p = 0; p < 4; ++p) {
    int r = (tid >> 4) + p * 16;       // h row 0..63
    int c4 = (tid & 15) * 4;           // d col
    f32x4 v = *(const f32x4*)&V[((size_t)(b * SQ + h0 + r)) * DM + d0 + c4];
#pragma unroll
    for (int j = 0; j < 4; ++j) sT[(c4 + j) * 72 + r] = (__bf16)v[j];
  }
  __syncthreads();
#pragma unroll
  for (int p = 0; p < 2; ++p) {
    int d = (tid >> 3) + p * 32;       // d row 0..63
    int hc = (tid & 7) * 8;            // h chunk
    u32x4 val = *(const u32x4*)&sT[d * 72 + hc];
    *(u32x4*)&Vt[((size_t)(b * DM + d0 + d)) * SQ + h0 + hc] = val;
  }
}

// ---------------- scores: E = exp((Tb . Hb^T)/32), invl = 1/rowsum ----------------
// grid (32, 8): x = 64-row strip of t, y = batch.  512 threads = 8 waves (2M x 4N).
__launch_bounds__(512)
__global__ void k_scores(const __bf16* __restrict__ Tb, const __bf16* __restrict__ Hb,
                         __bf16* __restrict__ E, float* __restrict__ invl) {
  __shared__ alignas(16) __bf16 sA[2][64 * 64];
  __shared__ alignas(16) __bf16 sB[2][256 * 64];
  __shared__ float s_rs4[4][64];
  const int tid = threadIdx.x;
  const int b = blockIdx.y;
  const int t0 = blockIdx.x * 64;
  const int w = tid >> 6, lane = tid & 63;
  const int wm = w >> 2, wn = w & 3;     // 2 x 4 wave grid
  const int lr = lane & 15, lg = lane >> 4;

  const int sr = tid >> 3;               // staging row 0..63
  const int sc = tid & 7;                // physical chunk 0..7
  // pre-swizzled global source: physical chunk sc holds logical chunk sc^(sr&7)
  const __bf16* Abase = Tb + ((size_t)(b * SQ + t0 + sr)) * DM + ((sc ^ (sr & 7)) * 8);
  const size_t brow = (size_t)64 * DM;   // B rep stride (64 rows); (r&7) unchanged

  float rs[2][4];
#pragma unroll
  for (int m = 0; m < 2; ++m)
#pragma unroll
    for (int i = 0; i < 4; ++i) rs[m][i] = 0.f;

  for (int nt = 0; nt < 8; ++nt) {
    const int h0 = nt * 256;
    const __bf16* Bbase = Hb + ((size_t)(b * SQ + h0 + sr)) * DM + ((sc ^ (sr & 7)) * 8);

    f32x4 acc[2][4];
#pragma unroll
    for (int m = 0; m < 2; ++m)
#pragma unroll
      for (int n = 0; n < 4; ++n) acc[m][n] = (f32x4){0.f, 0.f, 0.f, 0.f};

    // prologue: stage kt=0 into buf 0
    {
      u32x4 ra = *(const u32x4*)(Abase);
      u32x4 rb[4];
#pragma unroll
      for (int rep = 0; rep < 4; ++rep) rb[rep] = *(const u32x4*)(Bbase + rep * brow);
      *(u32x4*)&sA[0][sr * 64 + sc * 8] = ra;
#pragma unroll
      for (int rep = 0; rep < 4; ++rep)
        *(u32x4*)&sB[0][(sr + rep * 64) * 64 + sc * 8] = rb[rep];
    }
    __syncthreads();

    int cur = 0;
    for (int kt = 0; kt < 16; ++kt) {
      u32x4 na, nb[4];
      const bool more = (kt + 1 < 16);
      if (more) {  // issue next-tile loads early; latency hides under MFMA
        na = *(const u32x4*)(Abase + (kt + 1) * 64);
#pragma unroll
        for (int rep = 0; rep < 4; ++rep)
          nb[rep] = *(const u32x4*)(Bbase + rep * brow + (kt + 1) * 64);
      }
      const __bf16* A = sA[cur];
      const __bf16* Bt = sB[cur];
#pragma unroll
      for (int ks = 0; ks < 2; ++ks) {
        bf16x8 af[2], bfr[4];
#pragma unroll
        for (int m = 0; m < 2; ++m) af[m] = ldfrag(A, wm * 32 + m * 16 + lr, ks * 4 + lg);
#pragma unroll
        for (int n = 0; n < 4; ++n) bfr[n] = ldfrag(Bt, wn * 64 + n * 16 + lr, ks * 4 + lg);
#pragma unroll
        for (int m = 0; m < 2; ++m)
#pragma unroll
          for (int n = 0; n < 4; ++n)
            acc[m][n] = __builtin_amdgcn_mfma_f32_16x16x32_bf16(af[m], bfr[n], acc[m][n], 0, 0, 0);
      }
      if (more) {
        *(u32x4*)&sA[cur ^ 1][sr * 64 + sc * 8] = na;
#pragma unroll
        for (int rep = 0; rep < 4; ++rep)
          *(u32x4*)&sB[cur ^ 1][(sr + rep * 64) * 64 + sc * 8] = nb[rep];
      }
      __syncthreads();
      cur ^= 1;
    }

    // epilogue: exp, store E bf16, accumulate row-sum partials
#pragma unroll
    for (int m = 0; m < 2; ++m)
#pragma unroll
      for (int n = 0; n < 4; ++n)
#pragma unroll
        for (int i = 0; i < 4; ++i) {
          float e = __expf(acc[m][n][i] * 0.03125f);
          int rowl = wm * 32 + m * 16 + lg * 4 + i;
          int col = h0 + wn * 64 + n * 16 + lr;
          E[((size_t)(b * SQ + t0 + rowl)) * SQ + col] = (__bf16)e;
          rs[m][i] += e;
        }
  }

  // reduce row sums: over the 16 lanes of each lane-group, then across the 4 N-wave columns
#pragma unroll
  for (int m = 0; m < 2; ++m)
#pragma unroll
    for (int i = 0; i < 4; ++i) {
      float v = rs[m][i];
#pragma unroll
      for (int off = 1; off < 16; off <<= 1) v += __shfl_xor(v, off);
      if (lr == 0) s_rs4[wn][wm * 32 + m * 16 + lg * 4 + i] = v;
    }
  __syncthreads();
  if (tid < 64) {
    float s = s_rs4[0][tid] + s_rs4[1][tid] + s_rs4[2][tid] + s_rs4[3][tid];
    invl[b * SQ + t0 + tid] = 1.0f / s;
  }
}

// ---------------- O = (E . Vt^T-layout) * invl ----------------
// grid (16, 8, 8): x = t tile (128), y = d tile (128), z = batch. 512 thr = 8 waves (4M x 2N).
__launch_bounds__(512)
__global__ void k_pv(const __bf16* __restrict__ E, const __bf16* __restrict__ Vt,
                     const float* __restrict__ invl, float* __restrict__ out) {
  __shared__ alignas(16) __bf16 sA[2][128 * 64];
  __shared__ alignas(16) __bf16 sB[2][128 * 64];
  __shared__ float s_inv[128];
  const int tid = threadIdx.x;
  const int b = blockIdx.z;
  const int t0 = blockIdx.x * 128, d0 = blockIdx.y * 128;
  const int w = tid >> 6, lane = tid & 63;
  const int wm = w >> 1, wn = w & 1;     // 4 x 2 wave grid
  const int lr = lane & 15, lg = lane >> 4;
  if (tid < 128) s_inv[tid] = invl[b * SQ + t0 + tid];

  const int sr = tid >> 3, sc = tid & 7;
  const __bf16* Abase = E + ((size_t)(b * SQ + t0 + sr)) * SQ + ((sc ^ (sr & 7)) * 8);
  const __bf16* Bbase = Vt + ((size_t)(b * DM + d0 + sr)) * SQ + ((sc ^ (sr & 7)) * 8);
  const size_t rrow = (size_t)64 * SQ;   // 64-row rep stride

  f32x4 acc[2][4];
#pragma unroll
  for (int m = 0; m < 2; ++m)
#pragma unroll
    for (int n = 0; n < 4; ++n) acc[m][n] = (f32x4){0.f, 0.f, 0.f, 0.f};

  // prologue: stage kt=0 into buf 0
  {
    u32x4 ra[2], rb[2];
#pragma unroll
    for (int rep = 0; rep < 2; ++rep) {
      ra[rep] = *(const u32x4*)(Abase + rep * rrow);
      rb[rep] = *(const u32x4*)(Bbase + rep * rrow);
    }
#pragma unroll
    for (int rep = 0; rep < 2; ++rep) {
      *(u32x4*)&sA[0][(sr + rep * 64) * 64 + sc * 8] = ra[rep];
      *(u32x4*)&sB[0][(sr + rep * 64) * 64 + sc * 8] = rb[rep];
    }
  }
  __syncthreads();

  int cur = 0;
  for (int kt = 0; kt < 32; ++kt) {
    u32x4 na[2], nb[2];
    const bool more = (kt + 1 < 32);
    if (more) {
#pragma unroll
      for (int rep = 0; rep < 2; ++rep) {
        na[rep] = *(const u32x4*)(Abase + rep * rrow + (kt + 1) * 64);
        nb[rep] = *(const u32x4*)(Bbase + rep * rrow + (kt + 1) * 64);
      }
    }
    const __bf16* A = sA[cur];
    const __bf16* Bt = sB[cur];
#pragma unroll
    for (int ks = 0; ks < 2; ++ks) {
      bf16x8 af[2], bfr[4];
#pragma unroll
      for (int m = 0; m < 2; ++m) af[m] = ldfrag(A, wm * 32 + m * 16 + lr, ks * 4 + lg);
#pragma unroll
      for (int n = 0; n < 4; ++n) bfr[n] = ldfrag(Bt, wn * 64 + n * 16 + lr, ks * 4 + lg);
#pragma unroll
      for (int m = 0; m < 2; ++m)
#pragma unroll
        for (int n = 0; n < 4; ++n)
          acc[m][n] = __builtin_amdgcn_mfma_f32_16x16x32_bf16(af[m], bfr[n], acc[m][n], 0, 0, 0);
    }
    if (more) {
#pragma unroll
      for (int rep = 0; rep < 2; ++rep) {
        *(u32x4*)&sA[cur ^ 1][(sr + rep * 64) * 64 + sc * 8] = na[rep];
        *(u32x4*)&sB[cur ^ 1][(sr + rep * 64) * 64 + sc * 8] = nb[rep];
      }
    }
    __syncthreads();
    cur ^= 1;
  }

  // epilogue: normalize, store fp32
#pragma unroll
  for (int m = 0; m < 2; ++m)
#pragma unroll
    for (int n = 0; n < 4; ++n)
#pragma unroll
      for (int i = 0; i < 4; ++i) {
        int rowl = wm * 32 + m * 16 + lg * 4 + i;
        int col = wn * 64 + n * 16 + lr;
        out[((size_t)(b * SQ + t0 + rowl)) * DM + d0 + col] = acc[m][n][i] * s_inv[rowl];
      }
}

extern "C" void kernel_launch(void* const* d_in, const int* in_sizes, int n_in,
                              void* d_out, int out_size, void* d_ws, size_t ws_size,
                              hipStream_t stream) {
  const float* head = (const float*)d_in[0];  // K
  const float* tail = (const float*)d_in[1];  // Q and V
  float* out = (float*)d_out;
  char* ws = (char*)d_ws;

  const size_t SZ_BF = (size_t)NB * SQ * DM * 2;   // 33,554,432 B
  __bf16* Tb = (__bf16*)(ws);
  __bf16* Hb = (__bf16*)(ws + SZ_BF);
  __bf16* Vt = (__bf16*)(ws + 2 * SZ_BF);
  __bf16* E  = (__bf16*)(ws + 3 * SZ_BF);          // 67,108,864 B
  float*  invl = (float*)(ws + 3 * SZ_BF + (size_t)NB * SQ * SQ * 2);

  const int nconv = (NB * SQ * DM) / 8 / 256;      // 8192 blocks
  k_convert<<<nconv, 256, 0, stream>>>(tail, Tb);
  k_convert<<<nconv, 256, 0, stream>>>(head, Hb);
  k_transpose<<<dim3(DM / 64, SQ / 64, NB), 256, 0, stream>>>(tail, Vt);
  k_scores<<<dim3(SQ / 64, NB), 512, 0, stream>>>(Tb, Hb, E, invl);
  k_pv<<<dim3(SQ / 128, DM / 128, NB), 512, 0, stream>>>(E, Vt, invl, out);
}

// Round 9
// 339.749 us; speedup vs baseline: 1.1123x; 1.1123x over previous
//
#include <hip/hip_runtime.h>
#include <stdint.h>

typedef __attribute__((ext_vector_type(4))) float f32x4;
typedef __attribute__((ext_vector_type(4))) unsigned int u32x4;
typedef __attribute__((ext_vector_type(8))) __bf16 bf16x8;
typedef __attribute__((ext_vector_type(4))) __bf16 bf16x4;

#define NB 8
#define SQ 2048
#define DM 1024

// ---- async global->LDS 16B (linear dest = wave-uniform base + lane*16) ----
__device__ __forceinline__ void gload16(const void* g, void* l) {
  __builtin_amdgcn_global_load_lds(
      (const __attribute__((address_space(1))) void*)g,
      (__attribute__((address_space(3))) void*)l, 16, 0, 0);
}

__device__ __forceinline__ void memfence_bar() {
  asm volatile("" ::: "memory");
  __builtin_amdgcn_s_barrier();
  asm volatile("" ::: "memory");
}

// Fragment read from a [R][64] bf16 LDS tile (row stride 128 B) with XOR swizzle:
// logical chunk c (8 bf16 = 16 B) of row r lives at physical chunk c ^ (r & 7).
__device__ __forceinline__ bf16x8 ldfrag(const __bf16* base, int row, int chunk) {
  const char* p = (const char*)base + row * 128 + ((chunk ^ (row & 7)) << 4);
  return *(const bf16x8*)p;
}

// =======================================================================
// Ring-3 pipelined GEMM core: C[256 x 128] += A[256 x K] * B[128 x K]^T
// 512 threads = 8 waves as 4(M) x 2(N); per-wave 64x64 output.
// LDS: 3-slot ring of K-tiles (BK=64). Stage tile t+2 while consuming t;
// slot (t+2)%3 was last read by tile t-1 (finished a full group ago) -> safe.
// vmcnt(6) once per K-tile (= tile t+2's own 6 loads outstanding).
// =======================================================================
#define SLOTA (256 * 64)
#define SLOTB (128 * 64)

template <int NT>
__device__ __forceinline__ void gemm_core(const char* aBase, size_t ldaB,
                                          const char* bBase, size_t ldbB,
                                          __bf16* sA, __bf16* sB,
                                          f32x4 (&acc)[4][4]) {
  const int tid = threadIdx.x;
  const int w = tid >> 6, lane = tid & 63;
  const int wm = w >> 1, wn = w & 1;  // 4 x 2 wave grid
  const int lr = lane & 15, lg = lane >> 4;

  // staging: physical chunk p -> logical (row = p>>3, chunk = (p&7) ^ (row&7))
  const char* srcA[4];
  const char* srcB[2];
  int dstA[4], dstB[2];
#pragma unroll
  for (int i = 0; i < 4; ++i) {
    int p = i * 512 + tid, r = p >> 3, c = (p & 7) ^ (r & 7);
    srcA[i] = aBase + (size_t)r * ldaB + c * 16;
    dstA[i] = p * 8;
  }
#pragma unroll
  for (int i = 0; i < 2; ++i) {
    int p = i * 512 + tid, r = p >> 3, c = (p & 7) ^ (r & 7);
    srcB[i] = bBase + (size_t)r * ldbB + c * 16;
    dstB[i] = p * 8;
  }

  auto stageA = [&](int t, int i) {
    gload16(srcA[i] + (size_t)t * 128, sA + (t % 3) * SLOTA + dstA[i]);
  };
  auto stageB = [&](int t, int i) {
    gload16(srcB[i] + (size_t)t * 128, sB + (t % 3) * SLOTB + dstB[i]);
  };

  // prologue: stage tiles 0, 1 (12 loads); wait until tile 0 landed (6 left)
#pragma unroll
  for (int t = 0; t < 2; ++t) {
    stageA(t, 0); stageA(t, 1); stageA(t, 2); stageA(t, 3);
    stageB(t, 0); stageB(t, 1);
  }
  asm volatile("s_waitcnt vmcnt(6)" ::: "memory");
  memfence_bar();

  for (int t = 0; t < NT; ++t) {
    const __bf16* A = sA + (t % 3) * SLOTA;
    const __bf16* B = sB + (t % 3) * SLOTB;
    const bool st = (t + 2) < NT;

    // ---------------- phase 0 : ks = 0 ----------------
    bf16x8 af[4], bfv[4];
#pragma unroll
    for (int m = 0; m < 4; ++m) af[m] = ldfrag(A, wm * 64 + m * 16 + lr, lg);
#pragma unroll
    for (int n = 0; n < 4; ++n) bfv[n] = ldfrag(B, wn * 64 + n * 16 + lr, lg);
    if (st) { stageA(t + 2, 0); stageA(t + 2, 1); stageA(t + 2, 2); }
    memfence_bar();
    asm volatile("s_waitcnt lgkmcnt(0)" ::: "memory");
    __builtin_amdgcn_sched_barrier(0);
    __builtin_amdgcn_s_setprio(1);
#pragma unroll
    for (int m = 0; m < 4; ++m)
#pragma unroll
      for (int n = 0; n < 4; ++n)
        acc[m][n] = __builtin_amdgcn_mfma_f32_16x16x32_bf16(af[m], bfv[n], acc[m][n], 0, 0, 0);
    __builtin_amdgcn_s_setprio(0);
    memfence_bar();

    // ---------------- phase 1 : ks = 1 ----------------
#pragma unroll
    for (int m = 0; m < 4; ++m) af[m] = ldfrag(A, wm * 64 + m * 16 + lr, 4 + lg);
#pragma unroll
    for (int n = 0; n < 4; ++n) bfv[n] = ldfrag(B, wn * 64 + n * 16 + lr, 4 + lg);
    if (st) { stageA(t + 2, 3); stageB(t + 2, 0); stageB(t + 2, 1); }
    if (t < NT - 2) asm volatile("s_waitcnt vmcnt(6)" ::: "memory");
    else            asm volatile("s_waitcnt vmcnt(0)" ::: "memory");
    memfence_bar();
    asm volatile("s_waitcnt lgkmcnt(0)" ::: "memory");
    __builtin_amdgcn_sched_barrier(0);
    __builtin_amdgcn_s_setprio(1);
#pragma unroll
    for (int m = 0; m < 4; ++m)
#pragma unroll
      for (int n = 0; n < 4; ++n)
        acc[m][n] = __builtin_amdgcn_mfma_f32_16x16x32_bf16(af[m], bfv[n], acc[m][n], 0, 0, 0);
    __builtin_amdgcn_s_setprio(0);
    memfence_bar();
  }
}

// ---------------- head: fp32 -> bf16 convert (8 elems / thread) ----------------
__global__ void k_convert(const float* __restrict__ src, __bf16* __restrict__ dst) {
  size_t i = (size_t)blockIdx.x * blockDim.x + threadIdx.x;
  const f32x4* s = (const f32x4*)src + i * 2;
  f32x4 a = s[0], b = s[1];
  bf16x8 o;
  o[0] = (__bf16)a[0]; o[1] = (__bf16)a[1]; o[2] = (__bf16)a[2]; o[3] = (__bf16)a[3];
  o[4] = (__bf16)b[0]; o[5] = (__bf16)b[1]; o[6] = (__bf16)b[2]; o[7] = (__bf16)b[3];
  *((bf16x8*)dst + i) = o;
}

// ------- tail: fused convert (Tb) + transpose (Vt [b][d][h]) -------
__global__ void k_prep_tail(const float* __restrict__ V, __bf16* __restrict__ Tb,
                            __bf16* __restrict__ Vt) {
  __shared__ alignas(16) __bf16 sT[64 * 72];
  const int tid = threadIdx.x;
  const int d0 = blockIdx.x * 64, h0 = blockIdx.y * 64, b = blockIdx.z;
#pragma unroll
  for (int p = 0; p < 4; ++p) {
    int r = (tid >> 4) + p * 16;
    int c4 = (tid & 15) * 4;
    f32x4 v = *(const f32x4*)&V[((size_t)(b * SQ + h0 + r)) * DM + d0 + c4];
    bf16x4 o;
#pragma unroll
    for (int j = 0; j < 4; ++j) o[j] = (__bf16)v[j];
    *(bf16x4*)&Tb[((size_t)(b * SQ + h0 + r)) * DM + d0 + c4] = o;
#pragma unroll
    for (int j = 0; j < 4; ++j) sT[(c4 + j) * 72 + r] = o[j];
  }
  __syncthreads();
#pragma unroll
  for (int p = 0; p < 2; ++p) {
    int d = (tid >> 3) + p * 32;
    int hc = (tid & 7) * 8;
    u32x4 val = *(const u32x4*)&sT[d * 72 + hc];
    *(u32x4*)&Vt[((size_t)(b * DM + d0 + d)) * SQ + h0 + hc] = val;
  }
}

// -------- scores: E = exp((Tb.Hb^T)/32), lsum += rowsums (atomic) --------
// grid 1024: 8 mt x 16 nt x 8 b, XCD-swizzled so all 16 nt of a (b,mt) share an XCD.
__launch_bounds__(512, 1)
__global__ void k_scores(const __bf16* __restrict__ Tb, const __bf16* __restrict__ Hb,
                         __bf16* __restrict__ E, float* __restrict__ lsum) {
  __shared__ alignas(16) __bf16 sA[3 * SLOTA];
  __shared__ alignas(16) __bf16 sB[3 * SLOTB];
  const int bid = blockIdx.x;
  const int swz = (bid & 7) * 128 + (bid >> 3);   // 1024 blocks, %8==0 -> bijective
  const int b = swz >> 7, rem = swz & 127;
  const int mt = rem >> 4, nt = rem & 15;
  const int t0 = mt * 256, n0 = nt * 128;
  const int tid = threadIdx.x;
  const int w = tid >> 6, lane = tid & 63;
  const int wm = w >> 1, wn = w & 1;
  const int lr = lane & 15, lg = lane >> 4;

  f32x4 acc[4][4];
#pragma unroll
  for (int m = 0; m < 4; ++m)
#pragma unroll
    for (int n = 0; n < 4; ++n) acc[m][n] = (f32x4){0.f, 0.f, 0.f, 0.f};

  gemm_core<16>((const char*)(Tb + (size_t)(b * SQ + t0) * DM), (size_t)DM * 2,
                (const char*)(Hb + (size_t)(b * SQ + n0) * DM), (size_t)DM * 2,
                sA, sB, acc);

  // epilogue: exp, store E bf16, atomic row-sum partials
#pragma unroll
  for (int m = 0; m < 4; ++m) {
    float rsum[4] = {0.f, 0.f, 0.f, 0.f};
#pragma unroll
    for (int n = 0; n < 4; ++n)
#pragma unroll
      for (int i = 0; i < 4; ++i) {
        float e = __expf(acc[m][n][i] * 0.03125f);
        int rowl = wm * 64 + m * 16 + lg * 4 + i;
        int col = n0 + wn * 64 + n * 16 + lr;
        E[((size_t)(b * SQ + t0 + rowl)) * SQ + col] = (__bf16)e;
        rsum[i] += e;
      }
#pragma unroll
    for (int i = 0; i < 4; ++i) {
      float v = rsum[i];
      v += __shfl_xor(v, 1); v += __shfl_xor(v, 2);
      v += __shfl_xor(v, 4); v += __shfl_xor(v, 8);
      if (lr == 0)
        atomicAdd(&lsum[b * SQ + t0 + wm * 64 + m * 16 + lg * 4 + i], v);
    }
  }
}

// -------- pv: O = (E . Vt^T) / lsum, fp32 out --------
// grid 512: 8 mt x 8 dt x 8 b, XCD-swizzled so all 8 dt of a (b,mt) share an XCD.
__launch_bounds__(512, 1)
__global__ void k_pv(const __bf16* __restrict__ E, const __bf16* __restrict__ Vt,
                     const float* __restrict__ lsum, float* __restrict__ out) {
  __shared__ alignas(16) __bf16 sA[3 * SLOTA];
  __shared__ alignas(16) __bf16 sB[3 * SLOTB];
  __shared__ float s_inv[256];
  const int bid = blockIdx.x;
  const int swz = (bid & 7) * 64 + (bid >> 3);    // 512 blocks, %8==0 -> bijective
  const int b = swz >> 6, rem = swz & 63;
  const int mt = rem >> 3, dt = rem & 7;
  const int t0 = mt * 256, d0 = dt * 128;
  const int tid = threadIdx.x;
  const int w = tid >> 6, lane = tid & 63;
  const int wm = w >> 1, wn = w & 1;
  const int lr = lane & 15, lg = lane >> 4;

  if (tid < 256) s_inv[tid] = 1.0f / lsum[b * SQ + t0 + tid];

  f32x4 acc[4][4];
#pragma unroll
  for (int m = 0; m < 4; ++m)
#pragma unroll
    for (int n = 0; n < 4; ++n) acc[m][n] = (f32x4){0.f, 0.f, 0.f, 0.f};

  gemm_core<32>((const char*)(E + (size_t)(b * SQ + t0) * SQ), (size_t)SQ * 2,
                (const char*)(Vt + (size_t)(b * DM + d0) * SQ), (size_t)SQ * 2,
                sA, sB, acc);

  // epilogue: normalize, store fp32 (core ended with a barrier; s_inv visible)
#pragma unroll
  for (int m = 0; m < 4; ++m)
#pragma unroll
    for (int n = 0; n < 4; ++n)
#pragma unroll
      for (int i = 0; i < 4; ++i) {
        int rowl = wm * 64 + m * 16 + lg * 4 + i;
        int col = wn * 64 + n * 16 + lr;
        out[((size_t)(b * SQ + t0 + rowl)) * DM + d0 + col] =
            acc[m][n][i] * s_inv[rowl];
      }
}

extern "C" void kernel_launch(void* const* d_in, const int* in_sizes, int n_in,
                              void* d_out, int out_size, void* d_ws, size_t ws_size,
                              hipStream_t stream) {
  const float* head = (const float*)d_in[0];  // K
  const float* tail = (const float*)d_in[1];  // Q and V
  float* out = (float*)d_out;
  char* ws = (char*)d_ws;

  const size_t SZ_BF = (size_t)NB * SQ * DM * 2;  // 32 MiB
  __bf16* Tb = (__bf16*)(ws);
  __bf16* Hb = (__bf16*)(ws + SZ_BF);
  __bf16* Vt = (__bf16*)(ws + 2 * SZ_BF);
  __bf16* E = (__bf16*)(ws + 3 * SZ_BF);          // 64 MiB
  float* lsum = (float*)(ws + 3 * SZ_BF + (size_t)NB * SQ * SQ * 2);

  hipMemsetAsync(lsum, 0, (size_t)NB * SQ * 4, stream);

  const int nconv = (NB * SQ * DM) / 8 / 256;     // 8192 blocks
  k_convert<<<nconv, 256, 0, stream>>>(head, Hb);
  k_prep_tail<<<dim3(DM / 64, SQ / 64, NB), 256, 0, stream>>>(tail, Tb, Vt);
  k_scores<<<1024, 512, 0, stream>>>(Tb, Hb, E, lsum);
  k_pv<<<512, 512, 0, stream>>>(E, Vt, lsum, out);
}